// Round 10
// baseline (176.137 us; speedup 1.0000x reference)
//
#include <hip/hip_runtime.h>
#include <float.h>
#include <limits.h>
#include <stdint.h>

constexpr int N = 16384;
constexpr int K = 8192;
constexpr int D = 256;

typedef _Float16 half8_t __attribute__((ext_vector_type(8)));
typedef float float4_t __attribute__((ext_vector_type(4)));

// ---------------- fallback helper: row sum-of-squares ----------------
__global__ void vq_rowsq(const float* __restrict__ A, float* __restrict__ out) {
    int row = blockIdx.x;
    int lane = threadIdx.x;  // 64
    float4 v = ((const float4*)(A + (size_t)row * D))[lane];
    float s = v.x * v.x + v.y * v.y + v.z * v.z + v.w * v.w;
    #pragma unroll
    for (int o = 32; o > 0; o >>= 1) s += __shfl_down(s, o);
    if (lane == 0) out[row] = s;
}

// =======================================================================
// FAST PATH: 1-pass f16-hi MFMA screen; A from GLOBAL (reg dbuf), E via LDS
// =======================================================================
// Lane-linear tiled layouts (zero bank conflicts, verified R5/R6/R9):
//   Xh[rt*4096 + ds*512 + g*64 + q*16 + r15] chunks (g=localrow>>4)
//   Eh[(ct*8+ds)*512 + (lc>>4)*64 + q*16 + (lc&15)] chunks (lc=code&127)
// chunk = 16B (8 halves); q = dim-quad within the 32-dim step ds.

__global__ void vq_prep(const float* __restrict__ X, const float* __restrict__ E,
                        _Float16* __restrict__ Xh, _Float16* __restrict__ Eh,
                        float* __restrict__ esq) {
    int c = blockIdx.x * 256 + threadIdx.x;
    const int XCH = N * 32;  // X chunks; % 256 == 0 so blocks don't mix X/E
    if (c < XCH) {
        int row = c >> 5, q8 = c & 31;
        int ds = q8 >> 2, q = q8 & 3;
        int rt = row >> 7, lr = row & 127;
        int slot = ((lr >> 4) << 6) + (q << 4) + (lr & 15);
        size_t dst = ((size_t)rt * 4096 + ds * 512 + slot) * 8;
        const float4* s4 = (const float4*)(X + (size_t)row * D + q8 * 8);
        float4 v0 = s4[0], v1 = s4[1];
        float x[8] = {v0.x, v0.y, v0.z, v0.w, v1.x, v1.y, v1.z, v1.w};
        half8_t hh;
        #pragma unroll
        for (int i = 0; i < 8; i++) hh[i] = (_Float16)x[i];
        *(half8_t*)(Xh + dst) = hh;
    } else {
        int cc = c - XCH;
        int code = cc >> 5, q8 = cc & 31;
        int ds = q8 >> 2, q = q8 & 3;
        int ct = code >> 7, lc = code & 127;
        int slot = ((lc >> 4) << 6) + (q << 4) + (lc & 15);
        size_t dst = ((size_t)(ct * 8 + ds) * 512 + slot) * 8;
        const float4* s4 = (const float4*)(E + (size_t)code * D + q8 * 8);
        float4 v0 = s4[0], v1 = s4[1];
        float x[8] = {v0.x, v0.y, v0.z, v0.w, v1.x, v1.y, v1.z, v1.w};
        half8_t hh;
        float sq = 0.f;
        #pragma unroll
        for (int i = 0; i < 8; i++) {
            hh[i] = (_Float16)x[i];
            sq += x[i] * x[i];
        }
        *(half8_t*)(Eh + dst) = hh;
        #pragma unroll
        for (int o = 16; o > 0; o >>= 1) sq += __shfl_xor(sq, o);
        if ((threadIdx.x & 31) == 0) esq[code] = sq;
    }
}

__device__ __forceinline__ void ldg_lds16(const _Float16* g, _Float16* l) {
    __builtin_amdgcn_global_load_lds(
        (const __attribute__((address_space(1))) unsigned int*)g,
        (__attribute__((address_space(3))) unsigned int*)l, 16, 0, 0);
}

constexpr int CS = 8;             // K-split; grid = (128 rt) x (8 cs) = 1024
constexpr int KT = (K / 128) / CS;  // 8 128-code tiles per block
constexpr int NSTEP = KT * 8;     // 64 (ctile, ds) steps

// block: 256 thr = 4 waves, tile 128 rows x 128 codes, quadrant waves 2x2.
// A-frags: coalesced global_load from Xh, parity-double-buffered in REGISTERS
// (one-step lookahead; the per-step barrier's vmcnt drain covers them).
// E: global_load_lds double-buffer 2x8KB. LDS 32KB total (reduction reuse).
// VGPR ~150 -> launch_bounds(256,3): 3 blocks/CU = 12 waves/CU.
__global__ __launch_bounds__(256, 3) void vq_mfma(
    const _Float16* __restrict__ Xh, const _Float16* __restrict__ Eh,
    const float* __restrict__ esq, float4* __restrict__ pcand) {
    __shared__ _Float16 lds[16384];  // 32KB; E staging uses first 16KB

    const int t = threadIdx.x, w = t >> 6, lane = t & 63;
    const int rt = blockIdx.x;  // row tile
    const int cs = blockIdx.y;  // code split 0..7
    const int c15 = lane & 15, quad = lane >> 4;

    float best[16];
    int bidx[16];
    #pragma unroll
    for (int i = 0; i < 16; i++) { best[i] = FLT_MAX; bidx[i] = 0; }

    // wave w stages chunks [w*128, w*128+128) of the step's 512-chunk E region
    auto stageE = [&](int s) {
        const int ct = cs * KT + (s >> 3), ds = s & 7;
        const _Float16* src = Eh + (((size_t)ct * 8 + ds) * 512 + w * 128) * 8;
        _Float16* dst = lds + ((size_t)((s & 1) * 512 + w * 128)) * 8;
        ldg_lds16(src + (size_t)lane * 8, dst);
        ldg_lds16(src + (size_t)(64 + lane) * 8, dst + 64 * 8);
    };

    // A-frags direct from global (lane-linear: 64 lanes = 1KB contiguous)
    const half8_t* Xf = (const half8_t*)(Xh + (size_t)rt * 4096 * 8);
    const int arow = (w >> 1) * 256 + lane;  // + mt*64 + ds*512
    half8_t Areg[2][4];
    auto loadA = [&](int ds, int par) {
        #pragma unroll
        for (int mt = 0; mt < 4; mt++)
            Areg[par][mt] = Xf[ds * 512 + arow + mt * 64];
    };

    const half8_t* C = (const half8_t*)lds;
    const int bbase = (w & 1) * 256 + lane;  // + nt*64, + (s&1)*512

    float4_t acc[4][4];
    #pragma unroll
    for (int mt = 0; mt < 4; mt++)
        #pragma unroll
        for (int nt = 0; nt < 4; nt++) acc[mt][nt] = {0.f, 0.f, 0.f, 0.f};

    loadA(0, 0);
    stageE(0);

    #pragma unroll 2
    for (int s = 0; s < NSTEP; s++) {
        __syncthreads();  // drains E-stage + A-prefetch issued one step earlier
        if (s + 1 < NSTEP) {
            stageE(s + 1);
            loadA((s + 1) & 7, (s + 1) & 1);
        }

        const int b = (s & 1) * 512;
        half8_t B[4];
        #pragma unroll
        for (int nt = 0; nt < 4; nt++) B[nt] = C[b + bbase + nt * 64];

        #pragma unroll
        for (int mt = 0; mt < 4; mt++)
            #pragma unroll
            for (int nt = 0; nt < 4; nt++)
                acc[mt][nt] = __builtin_amdgcn_mfma_f32_16x16x32_f16(
                    Areg[s & 1][mt], B[nt], acc[mt][nt], 0, 0, 0);

        if ((s & 7) == 7) {  // ctile epilogue: s = esq - 2*dot; acc reset
            const int code0 = (cs * KT + (s >> 3)) * 128 + (w & 1) * 64;
            #pragma unroll
            for (int nt = 0; nt < 4; nt++) {
                const int code = code0 + nt * 16 + c15;
                const float eq = esq[code];
                #pragma unroll
                for (int mt = 0; mt < 4; mt++)
                    #pragma unroll
                    for (int rg = 0; rg < 4; rg++) {
                        float sc = fmaf(-2.f, acc[mt][nt][rg], eq);
                        int sl = mt * 4 + rg;
                        if (sc < best[sl]) { best[sl] = sc; bidx[sl] = code; }
                    }
            }
            #pragma unroll
            for (int mt = 0; mt < 4; mt++)
                #pragma unroll
                for (int nt = 0; nt < 4; nt++) acc[mt][nt] = {0.f, 0.f, 0.f, 0.f};
        }
    }

    // per-row top-2 over 32 contributors ((w&1) x c15); 32KB LDS reused
    __syncthreads();
    float* smin = (float*)lds;            // [32][128] = 16KB
    int* sidx = (int*)lds + 4096;         // [32][128] = 16KB
    const int cont = (w & 1) * 16 + c15;
    #pragma unroll
    for (int sl = 0; sl < 16; sl++) {
        int row = (w >> 1) * 64 + (sl >> 2) * 16 + quad * 4 + (sl & 3);
        smin[cont * 128 + row] = best[sl];
        sidx[cont * 128 + row] = bidx[sl];
    }
    __syncthreads();
    if (t < 128) {
        float m1 = FLT_MAX, m2 = FLT_MAX;
        int i1 = 0, i2 = 0;
        for (int c = 0; c < 32; c++) {
            float v = smin[c * 128 + t];
            int id = sidx[c * 128 + t];
            if (v < m1 || (v == m1 && id < i1)) {
                m2 = m1; i2 = i1; m1 = v; i1 = id;
            } else if (v < m2 || (v == m2 && id < i2)) {
                m2 = v; i2 = id;
            }
        }
        uint32_t pk = ((uint32_t)i1 << 13) | (uint32_t)(i2 & 8191);
        float4 out;
        out.x = m1; out.y = m2; out.z = __int_as_float((int)pk); out.w = 0.f;
        pcand[(size_t)(rt * 128 + t) * CS + cs] = out;
    }
}

__device__ __forceinline__ float wave_sum(float v) {
    #pragma unroll
    for (int o = 1; o < 64; o <<= 1) v += __shfl_xor(v, o);
    return v;
}

// margin-gated final. Screen err bound per score ~0.14 (10-sigma); EB=0.4.
// gap > EB: screen winner provably exact. Else: exact-fp32 rescore of only
// the candidates whose screened score <= gm1 + EB (superset of possible
// true winners since |screen-true| <= EB/2 per score).
__global__ void vq_rescore(const float* __restrict__ X, const float* __restrict__ E,
                           const float4* __restrict__ pcand, float* __restrict__ out_q,
                           float* __restrict__ out_idx) {
    constexpr float EB = 0.4f;
    int row = blockIdx.x * 4 + (threadIdx.x >> 6);
    int lane = threadIdx.x & 63;

    int cand[2 * CS];
    float csc[2 * CS];
    float gm1 = FLT_MAX, gm2 = FLT_MAX;
    int gi1 = INT_MAX;
    #pragma unroll
    for (int s = 0; s < CS; s++) {
        float4 p = pcand[(size_t)row * CS + s];
        uint32_t pk = (uint32_t)__float_as_int(p.z);
        int i1 = (int)(pk >> 13), i2 = (int)(pk & 8191);
        cand[2 * s] = i1;
        csc[2 * s] = p.x;
        cand[2 * s + 1] = i2;
        csc[2 * s + 1] = p.y;
        if (p.x < gm1 || (p.x == gm1 && i1 < gi1)) {
            gm2 = gm1; gm1 = p.x; gi1 = i1;
        } else if (p.x < gm2) gm2 = p.x;
        if (p.y < gm2) gm2 = p.y;
    }

    int besti = gi1;
    if (gm2 - gm1 <= EB) {  // ambiguous: exact fp32 rescore of survivors
        float4 xv = ((const float4*)(X + (size_t)row * D))[lane];
        float xs = wave_sum(xv.x * xv.x + xv.y * xv.y + xv.z * xv.z + xv.w * xv.w);
        float bestv = FLT_MAX;
        besti = INT_MAX;
        for (int c = 0; c < 2 * CS; c++) {
            if (csc[c] > gm1 + EB) continue;  // cannot be the true winner
            int idx = cand[c];
            float4 e = ((const float4*)(E + (size_t)idx * D))[lane];
            float dp = wave_sum(xv.x * e.x + xv.y * e.y + xv.z * e.z + xv.w * e.w);
            float eq = wave_sum(e.x * e.x + e.y * e.y + e.z * e.z + e.w * e.w);
            float sc = (xs + eq) - 2.f * dp;
            if (sc < bestv || (sc == bestv && idx < besti)) { bestv = sc; besti = idx; }
        }
    }
    if (lane == 0) out_idx[row] = (float)besti;
    float4 bv = ((const float4*)(E + (size_t)besti * D))[lane];
    ((float4*)(out_q + (size_t)row * D))[lane] = bv;
}

// =======================================================================
// FALLBACK (proven R1 fp32 path) — used only if ws_size is too small
// =======================================================================
constexpr int BM = 128, BN = 128, DK = 32, KSPLIT = 8;
constexpr int KCHUNK = K / KSPLIT;
constexpr int LDX = BM + 4, LDE = BN + 4;

__global__ __launch_bounds__(256) void vq_main(
    const float* __restrict__ X, const float* __restrict__ E,
    const float* __restrict__ xsq, const float* __restrict__ esq,
    float* __restrict__ pmin, int* __restrict__ pidx) {
    __shared__ float sx[DK * LDX];
    __shared__ float se[DK * LDE];
    const int t = threadIdx.x;
    const int row0 = blockIdx.x * BM;
    const int kbeg = blockIdx.y * KCHUNK;
    const int lane = t & 63, wave = t >> 6;
    const int lm = lane >> 3, ln = lane & 7;
    const int mf = (wave >> 1) * 64 + lm * 8;
    const int nf = (wave & 1) * 64 + ln * 8;
    float xs[8];
    #pragma unroll
    for (int i = 0; i < 8; i++) xs[i] = xsq[row0 + mf + i];
    float rmin[8];
    int ridx[8];
    #pragma unroll
    for (int i = 0; i < 8; i++) { rmin[i] = FLT_MAX; ridx[i] = 0; }
    const int sm = t >> 3;
    const int sd = (t & 7) * 4;
    for (int kt = kbeg; kt < kbeg + KCHUNK; kt += BN) {
        float acc[8][8];
        #pragma unroll
        for (int i = 0; i < 8; i++)
            #pragma unroll
            for (int j = 0; j < 8; j++) acc[i][j] = 0.0f;
        for (int d0 = 0; d0 < D; d0 += DK) {
            __syncthreads();
            #pragma unroll
            for (int r = 0; r < 4; r++) {
                int row = sm + 32 * r;
                float4 v = *(const float4*)(X + (size_t)(row0 + row) * D + d0 + sd);
                sx[(sd + 0) * LDX + row] = v.x;
                sx[(sd + 1) * LDX + row] = v.y;
                sx[(sd + 2) * LDX + row] = v.z;
                sx[(sd + 3) * LDX + row] = v.w;
                float4 ww = *(const float4*)(E + (size_t)(kt + row) * D + d0 + sd);
                se[(sd + 0) * LDE + row] = ww.x;
                se[(sd + 1) * LDE + row] = ww.y;
                se[(sd + 2) * LDE + row] = ww.z;
                se[(sd + 3) * LDE + row] = ww.w;
            }
            __syncthreads();
            #pragma unroll
            for (int d = 0; d < DK; d++) {
                float4 a0 = *(const float4*)(sx + d * LDX + mf);
                float4 a1 = *(const float4*)(sx + d * LDX + mf + 4);
                float4 b0 = *(const float4*)(se + d * LDE + nf);
                float4 b1 = *(const float4*)(se + d * LDE + nf + 4);
                float a[8] = {a0.x, a0.y, a0.z, a0.w, a1.x, a1.y, a1.z, a1.w};
                float b[8] = {b0.x, b0.y, b0.z, b0.w, b1.x, b1.y, b1.z, b1.w};
                #pragma unroll
                for (int i = 0; i < 8; i++)
                    #pragma unroll
                    for (int j = 0; j < 8; j++) acc[i][j] += a[i] * b[j];
            }
        }
        float es[8];
        #pragma unroll
        for (int j = 0; j < 8; j++) es[j] = esq[kt + nf + j];
        #pragma unroll
        for (int i = 0; i < 8; i++)
            #pragma unroll
            for (int j = 0; j < 8; j++) {
                float s = (xs[i] + es[j]) - 2.0f * acc[i][j];
                if (s < rmin[i]) { rmin[i] = s; ridx[i] = kt + nf + j; }
            }
    }
    __syncthreads();
    float* redm = sx;
    int* redi = (int*)se;
    const int c = (wave & 1) * 8 + ln;
    #pragma unroll
    for (int i = 0; i < 8; i++) {
        int r = (wave >> 1) * 64 + lm * 8 + i;
        redm[r * 16 + c] = rmin[i];
        redi[r * 16 + c] = ridx[i];
    }
    __syncthreads();
    if (t < BM) {
        float bst = redm[t * 16];
        int bi = redi[t * 16];
        #pragma unroll
        for (int c2 = 1; c2 < 16; c2++) {
            float v = redm[t * 16 + c2];
            int id = redi[t * 16 + c2];
            if (v < bst || (v == bst && id < bi)) { bst = v; bi = id; }
        }
        pmin[(size_t)(row0 + t) * KSPLIT + blockIdx.y] = bst;
        pidx[(size_t)(row0 + t) * KSPLIT + blockIdx.y] = bi;
    }
}

__global__ void vq_final(const float* __restrict__ E, const float* __restrict__ pmin,
                         const int* __restrict__ pidx, float* __restrict__ out_q,
                         float* __restrict__ out_idx) {
    int row = blockIdx.x;
    int lane = threadIdx.x;
    float bst = pmin[(size_t)row * KSPLIT];
    int bi = pidx[(size_t)row * KSPLIT];
    #pragma unroll
    for (int s = 1; s < KSPLIT; s++) {
        float v = pmin[(size_t)row * KSPLIT + s];
        int id = pidx[(size_t)row * KSPLIT + s];
        if (v < bst || (v == bst && id < bi)) { bst = v; bi = id; }
    }
    if (lane == 0) out_idx[row] = (float)bi;
    float4 v = ((const float4*)(E + (size_t)bi * D))[lane];
    ((float4*)(out_q + (size_t)row * D))[lane] = v;
}

// =======================================================================
extern "C" void kernel_launch(void* const* d_in, const int* in_sizes, int n_in,
                              void* d_out, int out_size, void* d_ws, size_t ws_size,
                              hipStream_t stream) {
    const float* X = (const float*)d_in[0];  // [N, D]
    const float* E = (const float*)d_in[1];  // [K, D]
    float* out_q = (float*)d_out;
    float* out_idx = (float*)d_out + (size_t)N * D;

    // fast-path ws: Xh(8M) Eh(4M) esq(32K) pcand(N*CS*16 = 2M) ~= 14.3MB
    const size_t need = (size_t)12 * 1024 * 1024 + 32768 + (size_t)N * CS * 16;
    if (ws_size >= need) {
        _Float16* Xh = (_Float16*)d_ws;
        _Float16* Eh = Xh + (size_t)N * D;
        float* esq = (float*)(Eh + (size_t)K * D);
        float4* pcand = (float4*)(esq + K);

        vq_prep<<<(N + K) * 32 / 256, 256, 0, stream>>>(X, E, Xh, Eh, esq);
        dim3 grid(N / 128, CS);
        vq_mfma<<<grid, 256, 0, stream>>>(Xh, Eh, esq, pcand);
        vq_rescore<<<N / 4, 256, 0, stream>>>(X, E, pcand, out_q, out_idx);
    } else {
        float* esq = (float*)d_ws;
        float* xsq = esq + K;
        float* pmin = xsq + N;
        int* pidx = (int*)(pmin + (size_t)N * KSPLIT);
        vq_rowsq<<<K, 64, 0, stream>>>(E, esq);
        vq_rowsq<<<N, 64, 0, stream>>>(X, xsq);
        dim3 grid(N / BM, KSPLIT);
        vq_main<<<grid, 256, 0, stream>>>(X, E, xsq, esq, pmin, pidx);
        vq_final<<<N, 64, 0, stream>>>(E, pmin, pidx, out_q, out_idx);
    }
}

// Round 11
// 161.991 us; speedup vs baseline: 1.0873x; 1.0873x over previous
//
#include <hip/hip_runtime.h>
#include <float.h>
#include <limits.h>
#include <stdint.h>

constexpr int N = 16384;
constexpr int K = 8192;
constexpr int D = 256;

typedef _Float16 half8_t __attribute__((ext_vector_type(8)));
typedef float float4_t __attribute__((ext_vector_type(4)));

// ---------------- fallback helper: row sum-of-squares ----------------
__global__ void vq_rowsq(const float* __restrict__ A, float* __restrict__ out) {
    int row = blockIdx.x;
    int lane = threadIdx.x;  // 64
    float4 v = ((const float4*)(A + (size_t)row * D))[lane];
    float s = v.x * v.x + v.y * v.y + v.z * v.z + v.w * v.w;
    #pragma unroll
    for (int o = 32; o > 0; o >>= 1) s += __shfl_down(s, o);
    if (lane == 0) out[row] = s;
}

// =======================================================================
// FAST PATH: 1-pass f16-hi MFMA screen, BARRIER-FREE K-loop
//   X: LDS-resident (staged once, 1 barrier total)
//   E: global -> registers, one-step double buffer (no LDS, no barriers)
// =======================================================================
// Lane-linear tiled layouts (zero bank conflicts, verified R5/R6/R9):
//   Xh[rt*4096 + ds*512 + g*64 + q*16 + r15] chunks (g=localrow>>4)
//   Eh[(ct*8+ds)*512 + (lc>>4)*64 + q*16 + (lc&15)] chunks (lc=code&127)
// chunk = 16B (8 halves); q = dim-quad within the 32-dim step ds.

__global__ void vq_prep(const float* __restrict__ X, const float* __restrict__ E,
                        _Float16* __restrict__ Xh, _Float16* __restrict__ Eh,
                        float* __restrict__ esq) {
    int c = blockIdx.x * 256 + threadIdx.x;
    const int XCH = N * 32;  // X chunks; % 256 == 0 so blocks don't mix X/E
    if (c < XCH) {
        int row = c >> 5, q8 = c & 31;
        int ds = q8 >> 2, q = q8 & 3;
        int rt = row >> 7, lr = row & 127;
        int slot = ((lr >> 4) << 6) + (q << 4) + (lr & 15);
        size_t dst = ((size_t)rt * 4096 + ds * 512 + slot) * 8;
        const float4* s4 = (const float4*)(X + (size_t)row * D + q8 * 8);
        float4 v0 = s4[0], v1 = s4[1];
        float x[8] = {v0.x, v0.y, v0.z, v0.w, v1.x, v1.y, v1.z, v1.w};
        half8_t hh;
        #pragma unroll
        for (int i = 0; i < 8; i++) hh[i] = (_Float16)x[i];
        *(half8_t*)(Xh + dst) = hh;
    } else {
        int cc = c - XCH;
        int code = cc >> 5, q8 = cc & 31;
        int ds = q8 >> 2, q = q8 & 3;
        int ct = code >> 7, lc = code & 127;
        int slot = ((lc >> 4) << 6) + (q << 4) + (lc & 15);
        size_t dst = ((size_t)(ct * 8 + ds) * 512 + slot) * 8;
        const float4* s4 = (const float4*)(E + (size_t)code * D + q8 * 8);
        float4 v0 = s4[0], v1 = s4[1];
        float x[8] = {v0.x, v0.y, v0.z, v0.w, v1.x, v1.y, v1.z, v1.w};
        half8_t hh;
        float sq = 0.f;
        #pragma unroll
        for (int i = 0; i < 8; i++) {
            hh[i] = (_Float16)x[i];
            sq += x[i] * x[i];
        }
        *(half8_t*)(Eh + dst) = hh;
        #pragma unroll
        for (int o = 16; o > 0; o >>= 1) sq += __shfl_xor(sq, o);
        if ((threadIdx.x & 31) == 0) esq[code] = sq;
    }
}

__device__ __forceinline__ void ldg_lds16(const _Float16* g, _Float16* l) {
    __builtin_amdgcn_global_load_lds(
        (const __attribute__((address_space(1))) unsigned int*)g,
        (__attribute__((address_space(3))) unsigned int*)l, 16, 0, 0);
}

constexpr int CS = 8;             // K-split; grid = (128 rt) x (8 cs) = 1024
constexpr int KT = (K / 128) / CS;  // 8 128-code tiles per block
constexpr int NSTEP = KT * 8;     // 64 (ctile, ds) steps

// block: 256 thr = 4 waves, tile 128 rows x 128 codes, quadrant waves 2x2.
// LDS 64KB = X tile resident (staged once). E: per-step register dbuf from
// global (4 x half8 per wave = 1KB coalesced each). NO barrier in the loop:
// compiler emits fine-grained vmcnt/lgkmcnt, waves drift and self-overlap.
__global__ __launch_bounds__(256, 2) void vq_mfma(
    const _Float16* __restrict__ Xh, const _Float16* __restrict__ Eh,
    const float* __restrict__ esq, float4* __restrict__ pcand) {
    __shared__ _Float16 lds[32768];  // 4096 chunks x 16B = 64KB (X resident)

    const int t = threadIdx.x, w = t >> 6, lane = t & 63;
    const int rt = blockIdx.x;  // row tile
    const int cs = blockIdx.y;  // code split 0..7
    const int c15 = lane & 15, quad = lane >> 4;

    float best[16];
    int bidx[16];
    #pragma unroll
    for (int i = 0; i < 16; i++) { best[i] = FLT_MAX; bidx[i] = 0; }

    // ---- stage the whole X tile once: wave w -> chunks [w*1024, w*1024+1024)
    {
        const _Float16* src = Xh + ((size_t)rt * 4096 + w * 1024) * 8;
        _Float16* dst = lds + (size_t)(w * 1024) * 8;
        #pragma unroll
        for (int i = 0; i < 16; i++)
            ldg_lds16(src + (size_t)(i * 64 + lane) * 8, dst + i * 512);
    }

    const half8_t* C = (const half8_t*)lds;
    const int abase = (w >> 1) * 256 + lane;  // + mt*64 + ds*512
    // B frag global base (chunk units): wave (w&1) owns codes (w&1)*64..+63
    const half8_t* Bf = (const half8_t*)Eh;
    const int bbase = (w & 1) * 256 + lane;   // + nt*64 + (ct*8+ds)*512

    float4_t acc[4][4];
    #pragma unroll
    for (int mt = 0; mt < 4; mt++)
        #pragma unroll
        for (int nt = 0; nt < 4; nt++) acc[mt][nt] = {0.f, 0.f, 0.f, 0.f};

    half8_t Breg[2][4];
    auto loadB = [&](int s, int par) {
        const size_t rbase = (size_t)(cs * KT * 8 + s) * 512 + bbase;
        #pragma unroll
        for (int nt = 0; nt < 4; nt++) Breg[par][nt] = Bf[rbase + nt * 64];
    };

    loadB(0, 0);
    __syncthreads();  // the ONLY barrier: X tile visible to all waves

    #pragma unroll 2
    for (int s = 0; s < NSTEP; s++) {
        if (s + 1 < NSTEP) loadB(s + 1, (s + 1) & 1);

        const int ds = s & 7;
        half8_t A[4];
        #pragma unroll
        for (int mt = 0; mt < 4; mt++) A[mt] = C[ds * 512 + abase + mt * 64];

        #pragma unroll
        for (int mt = 0; mt < 4; mt++)
            #pragma unroll
            for (int nt = 0; nt < 4; nt++)
                acc[mt][nt] = __builtin_amdgcn_mfma_f32_16x16x32_f16(
                    A[mt], Breg[s & 1][nt], acc[mt][nt], 0, 0, 0);

        if ((s & 7) == 7) {  // ctile epilogue: sc = esq - 2*dot; acc reset
            const int code0 = (cs * KT + (s >> 3)) * 128 + (w & 1) * 64;
            #pragma unroll
            for (int nt = 0; nt < 4; nt++) {
                const int code = code0 + nt * 16 + c15;
                const float eq = esq[code];
                #pragma unroll
                for (int mt = 0; mt < 4; mt++)
                    #pragma unroll
                    for (int rg = 0; rg < 4; rg++) {
                        float sc = fmaf(-2.f, acc[mt][nt][rg], eq);
                        int sl = mt * 4 + rg;
                        if (sc < best[sl]) { best[sl] = sc; bidx[sl] = code; }
                    }
            }
            #pragma unroll
            for (int mt = 0; mt < 4; mt++)
                #pragma unroll
                for (int nt = 0; nt < 4; nt++) acc[mt][nt] = {0.f, 0.f, 0.f, 0.f};
        }
    }

    // per-row top-2 over 32 contributors ((w&1) x c15); LDS reused
    __syncthreads();
    float* smin = (float*)lds;            // [32][128] = 16KB
    int* sidx = (int*)lds + 4096;         // [32][128] = 16KB
    const int cont = (w & 1) * 16 + c15;
    #pragma unroll
    for (int sl = 0; sl < 16; sl++) {
        int row = (w >> 1) * 64 + (sl >> 2) * 16 + quad * 4 + (sl & 3);
        smin[cont * 128 + row] = best[sl];
        sidx[cont * 128 + row] = bidx[sl];
    }
    __syncthreads();
    if (t < 128) {
        float m1 = FLT_MAX, m2 = FLT_MAX;
        int i1 = 0, i2 = 0;
        for (int c = 0; c < 32; c++) {
            float v = smin[c * 128 + t];
            int id = sidx[c * 128 + t];
            if (v < m1 || (v == m1 && id < i1)) {
                m2 = m1; i2 = i1; m1 = v; i1 = id;
            } else if (v < m2 || (v == m2 && id < i2)) {
                m2 = v; i2 = id;
            }
        }
        uint32_t pk = ((uint32_t)i1 << 13) | (uint32_t)(i2 & 8191);
        float4 out;
        out.x = m1; out.y = m2; out.z = __int_as_float((int)pk); out.w = 0.f;
        pcand[(size_t)(rt * 128 + t) * CS + cs] = out;
    }
}

__device__ __forceinline__ float wave_sum(float v) {
    #pragma unroll
    for (int o = 1; o < 64; o <<= 1) v += __shfl_xor(v, o);
    return v;
}

// margin-gated final. Screen err bound per score ~0.14 (10-sigma); EB=0.4.
// gap > EB: screen winner provably exact. Else: exact-fp32 rescore of only
// candidates with screened score <= gm1 + EB.
__global__ void vq_rescore(const float* __restrict__ X, const float* __restrict__ E,
                           const float4* __restrict__ pcand, float* __restrict__ out_q,
                           float* __restrict__ out_idx) {
    constexpr float EB = 0.4f;
    int row = blockIdx.x * 4 + (threadIdx.x >> 6);
    int lane = threadIdx.x & 63;

    int cand[2 * CS];
    float csc[2 * CS];
    float gm1 = FLT_MAX, gm2 = FLT_MAX;
    int gi1 = INT_MAX;
    #pragma unroll
    for (int s = 0; s < CS; s++) {
        float4 p = pcand[(size_t)row * CS + s];
        uint32_t pk = (uint32_t)__float_as_int(p.z);
        int i1 = (int)(pk >> 13), i2 = (int)(pk & 8191);
        cand[2 * s] = i1;
        csc[2 * s] = p.x;
        cand[2 * s + 1] = i2;
        csc[2 * s + 1] = p.y;
        if (p.x < gm1 || (p.x == gm1 && i1 < gi1)) {
            gm2 = gm1; gm1 = p.x; gi1 = i1;
        } else if (p.x < gm2) gm2 = p.x;
        if (p.y < gm2) gm2 = p.y;
    }

    int besti = gi1;
    if (gm2 - gm1 <= EB) {  // ambiguous: exact fp32 rescore of survivors
        float4 xv = ((const float4*)(X + (size_t)row * D))[lane];
        float xs = wave_sum(xv.x * xv.x + xv.y * xv.y + xv.z * xv.z + xv.w * xv.w);
        float bestv = FLT_MAX;
        besti = INT_MAX;
        for (int c = 0; c < 2 * CS; c++) {
            if (csc[c] > gm1 + EB) continue;  // cannot be the true winner
            int idx = cand[c];
            float4 e = ((const float4*)(E + (size_t)idx * D))[lane];
            float dp = wave_sum(xv.x * e.x + xv.y * e.y + xv.z * e.z + xv.w * e.w);
            float eq = wave_sum(e.x * e.x + e.y * e.y + e.z * e.z + e.w * e.w);
            float sc = (xs + eq) - 2.f * dp;
            if (sc < bestv || (sc == bestv && idx < besti)) { bestv = sc; besti = idx; }
        }
    }
    if (lane == 0) out_idx[row] = (float)besti;
    float4 bv = ((const float4*)(E + (size_t)besti * D))[lane];
    ((float4*)(out_q + (size_t)row * D))[lane] = bv;
}

// =======================================================================
// FALLBACK (proven R1 fp32 path) — used only if ws_size is too small
// =======================================================================
constexpr int BM = 128, BN = 128, DK = 32, KSPLIT = 8;
constexpr int KCHUNK = K / KSPLIT;
constexpr int LDX = BM + 4, LDE = BN + 4;

__global__ __launch_bounds__(256) void vq_main(
    const float* __restrict__ X, const float* __restrict__ E,
    const float* __restrict__ xsq, const float* __restrict__ esq,
    float* __restrict__ pmin, int* __restrict__ pidx) {
    __shared__ float sx[DK * LDX];
    __shared__ float se[DK * LDE];
    const int t = threadIdx.x;
    const int row0 = blockIdx.x * BM;
    const int kbeg = blockIdx.y * KCHUNK;
    const int lane = t & 63, wave = t >> 6;
    const int lm = lane >> 3, ln = lane & 7;
    const int mf = (wave >> 1) * 64 + lm * 8;
    const int nf = (wave & 1) * 64 + ln * 8;
    float xs[8];
    #pragma unroll
    for (int i = 0; i < 8; i++) xs[i] = xsq[row0 + mf + i];
    float rmin[8];
    int ridx[8];
    #pragma unroll
    for (int i = 0; i < 8; i++) { rmin[i] = FLT_MAX; ridx[i] = 0; }
    const int sm = t >> 3;
    const int sd = (t & 7) * 4;
    for (int kt = kbeg; kt < kbeg + KCHUNK; kt += BN) {
        float acc[8][8];
        #pragma unroll
        for (int i = 0; i < 8; i++)
            #pragma unroll
            for (int j = 0; j < 8; j++) acc[i][j] = 0.0f;
        for (int d0 = 0; d0 < D; d0 += DK) {
            __syncthreads();
            #pragma unroll
            for (int r = 0; r < 4; r++) {
                int row = sm + 32 * r;
                float4 v = *(const float4*)(X + (size_t)(row0 + row) * D + d0 + sd);
                sx[(sd + 0) * LDX + row] = v.x;
                sx[(sd + 1) * LDX + row] = v.y;
                sx[(sd + 2) * LDX + row] = v.z;
                sx[(sd + 3) * LDX + row] = v.w;
                float4 ww = *(const float4*)(E + (size_t)(kt + row) * D + d0 + sd);
                se[(sd + 0) * LDE + row] = ww.x;
                se[(sd + 1) * LDE + row] = ww.y;
                se[(sd + 2) * LDE + row] = ww.z;
                se[(sd + 3) * LDE + row] = ww.w;
            }
            __syncthreads();
            #pragma unroll
            for (int d = 0; d < DK; d++) {
                float4 a0 = *(const float4*)(sx + d * LDX + mf);
                float4 a1 = *(const float4*)(sx + d * LDX + mf + 4);
                float4 b0 = *(const float4*)(se + d * LDE + nf);
                float4 b1 = *(const float4*)(se + d * LDE + nf + 4);
                float a[8] = {a0.x, a0.y, a0.z, a0.w, a1.x, a1.y, a1.z, a1.w};
                float b[8] = {b0.x, b0.y, b0.z, b0.w, b1.x, b1.y, b1.z, b1.w};
                #pragma unroll
                for (int i = 0; i < 8; i++)
                    #pragma unroll
                    for (int j = 0; j < 8; j++) acc[i][j] += a[i] * b[j];
            }
        }
        float es[8];
        #pragma unroll
        for (int j = 0; j < 8; j++) es[j] = esq[kt + nf + j];
        #pragma unroll
        for (int i = 0; i < 8; i++)
            #pragma unroll
            for (int j = 0; j < 8; j++) {
                float s = (xs[i] + es[j]) - 2.0f * acc[i][j];
                if (s < rmin[i]) { rmin[i] = s; ridx[i] = kt + nf + j; }
            }
    }
    __syncthreads();
    float* redm = sx;
    int* redi = (int*)se;
    const int c = (wave & 1) * 8 + ln;
    #pragma unroll
    for (int i = 0; i < 8; i++) {
        int r = (wave >> 1) * 64 + lm * 8 + i;
        redm[r * 16 + c] = rmin[i];
        redi[r * 16 + c] = ridx[i];
    }
    __syncthreads();
    if (t < BM) {
        float bst = redm[t * 16];
        int bi = redi[t * 16];
        #pragma unroll
        for (int c2 = 1; c2 < 16; c2++) {
            float v = redm[t * 16 + c2];
            int id = redi[t * 16 + c2];
            if (v < bst || (v == bst && id < bi)) { bst = v; bi = id; }
        }
        pmin[(size_t)(row0 + t) * KSPLIT + blockIdx.y] = bst;
        pidx[(size_t)(row0 + t) * KSPLIT + blockIdx.y] = bi;
    }
}

__global__ void vq_final(const float* __restrict__ E, const float* __restrict__ pmin,
                         const int* __restrict__ pidx, float* __restrict__ out_q,
                         float* __restrict__ out_idx) {
    int row = blockIdx.x;
    int lane = threadIdx.x;
    float bst = pmin[(size_t)row * KSPLIT];
    int bi = pidx[(size_t)row * KSPLIT];
    #pragma unroll
    for (int s = 1; s < KSPLIT; s++) {
        float v = pmin[(size_t)row * KSPLIT + s];
        int id = pidx[(size_t)row * KSPLIT + s];
        if (v < bst || (v == bst && id < bi)) { bst = v; bi = id; }
    }
    if (lane == 0) out_idx[row] = (float)bi;
    float4 v = ((const float4*)(E + (size_t)bi * D))[lane];
    ((float4*)(out_q + (size_t)row * D))[lane] = v;
}

// =======================================================================
extern "C" void kernel_launch(void* const* d_in, const int* in_sizes, int n_in,
                              void* d_out, int out_size, void* d_ws, size_t ws_size,
                              hipStream_t stream) {
    const float* X = (const float*)d_in[0];  // [N, D]
    const float* E = (const float*)d_in[1];  // [K, D]
    float* out_q = (float*)d_out;
    float* out_idx = (float*)d_out + (size_t)N * D;

    // fast-path ws: Xh(8M) Eh(4M) esq(32K) pcand(N*CS*16 = 2M) ~= 14.3MB
    const size_t need = (size_t)12 * 1024 * 1024 + 32768 + (size_t)N * CS * 16;
    if (ws_size >= need) {
        _Float16* Xh = (_Float16*)d_ws;
        _Float16* Eh = Xh + (size_t)N * D;
        float* esq = (float*)(Eh + (size_t)K * D);
        float4* pcand = (float4*)(esq + K);

        vq_prep<<<(N + K) * 32 / 256, 256, 0, stream>>>(X, E, Xh, Eh, esq);
        dim3 grid(N / 128, CS);
        vq_mfma<<<grid, 256, 0, stream>>>(Xh, Eh, esq, pcand);
        vq_rescore<<<N / 4, 256, 0, stream>>>(X, E, pcand, out_q, out_idx);
    } else {
        float* esq = (float*)d_ws;
        float* xsq = esq + K;
        float* pmin = xsq + N;
        int* pidx = (int*)(pmin + (size_t)N * KSPLIT);
        vq_rowsq<<<K, 64, 0, stream>>>(E, esq);
        vq_rowsq<<<N, 64, 0, stream>>>(X, xsq);
        dim3 grid(N / BM, KSPLIT);
        vq_main<<<grid, 256, 0, stream>>>(X, E, xsq, esq, pmin, pidx);
        vq_final<<<N, 64, 0, stream>>>(E, pmin, pidx, out_q, out_idx);
    }
}